// Round 1
// baseline (383.391 us; speedup 1.0000x reference)
//
#include <hip/hip_runtime.h>
#include <math.h>

#define D 128
#define LLEN 200
#define SLEN 50
#define NEGINF (-1e9f)

__device__ __forceinline__ float wave_red_max(float v) {
#pragma unroll
  for (int m = 32; m >= 1; m >>= 1) v = fmaxf(v, __shfl_xor(v, m, 64));
  return v;
}
__device__ __forceinline__ float wave_red_sum(float v) {
#pragma unroll
  for (int m = 32; m >= 1; m >>= 1) v += __shfl_xor(v, m, 64);
  return v;
}

// 256-thread block reductions; red is 4-float LDS scratch. ALL threads must call.
__device__ __forceinline__ float block_max(float v, float* red) {
  v = wave_red_max(v);
  if ((threadIdx.x & 63) == 0) red[threadIdx.x >> 6] = v;
  __syncthreads();
  v = fmaxf(fmaxf(red[0], red[1]), fmaxf(red[2], red[3]));
  __syncthreads();
  return v;
}
__device__ __forceinline__ float block_sum(float v, float* red) {
  v = wave_red_sum(v);
  if ((threadIdx.x & 63) == 0) red[threadIdx.x >> 6] = v;
  __syncthreads();
  v = red[0] + red[1] + red[2] + red[3];
  __syncthreads();
  return v;
}

// logit for one item: relu( u_part + e @ W1[128:256,:] ) @ W2 + b2
// ep may be global (item_table row) or LDS (u_long) -> generic pointer.
__device__ __forceinline__ float item_logit(const float* ep,
                                            const float* __restrict__ W1,
                                            const float* __restrict__ W2,
                                            const float* upart, float b2v) {
  float acc[16];
#pragma unroll
  for (int j = 0; j < 16; ++j) acc[j] = 0.f;

  for (int win = 0; win < 4; ++win) {  // 4 windows of 32 d's
    float e[32];
    const float4* ep4 = reinterpret_cast<const float4*>(ep) + win * 8;
#pragma unroll
    for (int t = 0; t < 8; ++t) {
      float4 v = ep4[t];
      e[4 * t + 0] = v.x; e[4 * t + 1] = v.y;
      e[4 * t + 2] = v.z; e[4 * t + 3] = v.w;
    }
    const float* wbase = W1 + (size_t)(D + win * 32) * 16;  // lane-uniform
#pragma unroll
    for (int dd = 0; dd < 32; ++dd) {
      float ev = e[dd];
#pragma unroll
      for (int j = 0; j < 16; ++j)
        acc[j] = fmaf(ev, wbase[dd * 16 + j], acc[j]);
    }
  }
  float hs = 0.f;
#pragma unroll
  for (int j = 0; j < 16; ++j)
    hs = fmaf(fmaxf(upart[j] + acc[j], 0.f), W2[j], hs);
  return hs + b2v;
}

__global__ void __launch_bounds__(256) din_kernel(
    const float* __restrict__ user_table, const float* __restrict__ item_table,
    const float* __restrict__ W1, const float* __restrict__ b1,
    const float* __restrict__ W2, const float* __restrict__ b2,
    const int* __restrict__ user_inputs, const int* __restrict__ L_inputs,
    const int* __restrict__ S_inputs, const int* __restrict__ item_inputs,
    float* __restrict__ out) {
  __shared__ float u_sh[D];
  __shared__ float upart_sh[16];
  __shared__ float w_sh[256];      // logits -> unnormalized weights
  __shared__ int rows_sh[256];     // gathered (clamped) row ids, stage1 then stage2
  __shared__ __align__(16) float ulong_sh[D];
  __shared__ float uh_sh[D];
  __shared__ float part_sh[256];
  __shared__ float red_sh[4];

  const int b = blockIdx.x;
  const int tid = threadIdx.x;

  // ---- user embedding ----
  const int uid = user_inputs[b];
  if (tid < D) u_sh[tid] = user_table[(size_t)uid * D + tid];
  __syncthreads();

  // ---- u_part[j] = b1[j] + u @ W1[0:128,:] ----
  {
    int j = tid & 15, g = tid >> 4;  // 16 groups x 16 j
    float p = 0.f;
#pragma unroll
    for (int dd = 0; dd < 8; ++dd) {
      int d = g * 8 + dd;
      p = fmaf(u_sh[d], W1[d * 16 + j], p);
    }
    part_sh[tid] = p;  // tid == g*16 + j
  }
  __syncthreads();
  if (tid < 16) {
    float s = b1[tid];
#pragma unroll
    for (int g = 0; g < 16; ++g) s += part_sh[g * 16 + tid];
    upart_sh[tid] = s;
  }
  __syncthreads();

  const float b2v = b2[0];

  // ---- stage 1: logits over L history (item-per-thread) ----
  float logit = NEGINF;
  if (tid < LLEN) {
    int idx = L_inputs[(size_t)b * LLEN + tid];
    int row = (idx >= 0) ? idx : 0;
    rows_sh[tid] = row;
    float lg = item_logit(item_table + (size_t)row * D, W1, W2, upart_sh, b2v);
    logit = (idx >= 0) ? lg : NEGINF;
  }
  float m1 = block_max(logit, red_sh);
  float p1 = (tid < LLEN) ? expf(logit - m1) : 0.f;
  if (tid < LLEN) w_sh[tid] = p1;
  float S1 = block_sum(p1, red_sh);  // barrier inside also publishes w_sh
  float invS1 = 1.f / S1;

  // ---- u_long[d] = (1/S1) * sum_l p_l * e_l[d] ----
  {
    int d = tid & (D - 1), h = tid >> 7;
    float acc = 0.f;
    for (int l = h; l < LLEN; l += 2)
      acc = fmaf(w_sh[l], item_table[(size_t)rows_sh[l] * D + d], acc);
    part_sh[tid] = acc;  // tid == h*128 + d
  }
  __syncthreads();
  if (tid < D) ulong_sh[tid] = (part_sh[tid] + part_sh[tid + D]) * invS1;
  __syncthreads();

  // ---- stage 2: logits over [u_long] + S (13 items per wave for balance) ----
  {
    int lane = tid & 63, wv = tid >> 6;
    int sitem = wv * 13 + lane;
    if (lane < 13 && sitem < SLEN + 1) {
      const float* ep;
      bool valid = true;
      int srow = 0;
      if (sitem == 0) {
        ep = ulong_sh;
      } else {
        int idx = S_inputs[(size_t)b * SLEN + (sitem - 1)];
        valid = (idx >= 0);
        srow = valid ? idx : 0;
        ep = item_table + (size_t)srow * D;
      }
      float lg = item_logit(ep, W1, W2, upart_sh, b2v);
      w_sh[sitem] = valid ? lg : NEGINF;
      rows_sh[sitem] = srow;
    }
  }
  __syncthreads();

  const int n2 = SLEN + 1;
  float lg2 = (tid < n2) ? w_sh[tid] : NEGINF;
  float m2 = block_max(lg2, red_sh);
  float p2 = (tid < n2) ? expf(lg2 - m2) : 0.f;
  float S2 = block_sum(p2, red_sh);
  if (tid < n2) w_sh[tid] = p2;
  __syncthreads();
  float invS2 = 1.f / S2;

  // ---- user_hybrid[d] ----
  {
    int d = tid & (D - 1), h = tid >> 7;
    float acc = 0.f;
    for (int s = h; s < n2; s += 2) {
      float ev = (s == 0) ? ulong_sh[d] : item_table[(size_t)rows_sh[s] * D + d];
      acc = fmaf(w_sh[s], ev, acc);
    }
    part_sh[tid] = acc;
  }
  __syncthreads();
  if (tid < D) uh_sh[tid] = (part_sh[tid] + part_sh[tid + D]) * invS2;
  __syncthreads();

  // ---- score = dot(user_hybrid, item_emb) ----
  float sv = 0.f;
  if (tid < D) {
    int irow = item_inputs[b];
    sv = uh_sh[tid] * item_table[(size_t)irow * D + tid];
  }
  float tot = block_sum(sv, red_sh);
  if (tid == 0) out[b] = tot;
}

extern "C" void kernel_launch(void* const* d_in, const int* in_sizes, int n_in,
                              void* d_out, int out_size, void* d_ws, size_t ws_size,
                              hipStream_t stream) {
  const float* user_table = (const float*)d_in[0];
  const float* item_table = (const float*)d_in[1];
  const float* W1 = (const float*)d_in[2];
  const float* b1 = (const float*)d_in[3];
  const float* W2 = (const float*)d_in[4];
  const float* b2 = (const float*)d_in[5];
  const int* user_inputs = (const int*)d_in[6];
  const int* L_inputs = (const int*)d_in[7];
  const int* S_inputs = (const int*)d_in[8];
  const int* item_inputs = (const int*)d_in[9];
  float* out = (float*)d_out;

  const int B = in_sizes[6];  // 4096
  din_kernel<<<B, 256, 0, stream>>>(user_table, item_table, W1, b1, W2, b2,
                                    user_inputs, L_inputs, S_inputs, item_inputs,
                                    out);
}